// Round 1
// baseline (1262.861 us; speedup 1.0000x reference)
//
#include <hip/hip_runtime.h>
#include <hip/hip_bf16.h>
#include <math.h>

// Problem constants (from reference)
#define HDIM 2048
#define IDIM 7168
#define NEXP 8
#define TTOK 2048
#define TOPK 2
#define NASSIGN (TTOK * TOPK)   // 4096 token-expert assignments
#define ROWCAP 5120             // 4096 + 8*128 padding headroom

#define BK 32                   // K-step (bf16 elems) per MFMA
#define LDK 40                  // padded LDS row length (80B = 20-bank stride)

typedef float  f32x4 __attribute__((ext_vector_type(4)));
typedef int    i32x4 __attribute__((ext_vector_type(4)));
typedef unsigned short u16;
typedef u16    u16x8 __attribute__((ext_vector_type(8)));

__device__ __forceinline__ u16 f2bf(float f) {
    return __builtin_bit_cast(u16, (__bf16)f);   // RNE, compiler can pair into v_cvt_pk_bf16_f32
}

__device__ __forceinline__ f32x4 mfma16(i32x4 a, i32x4 b, f32x4 c) {
    asm("v_mfma_f32_16x16x32_bf16 %0, %1, %2, %0" : "+v"(c) : "v"(a), "v"(b));
    return c;
}

__device__ __forceinline__ void cvt_store8(u16* dst, f32x4 a, f32x4 b) {
    u16x8 p;
    p[0]=f2bf(a[0]); p[1]=f2bf(a[1]); p[2]=f2bf(a[2]); p[3]=f2bf(a[3]);
    p[4]=f2bf(b[0]); p[5]=f2bf(b[1]); p[6]=f2bf(b[2]); p[7]=f2bf(b[3]);
    *(u16x8*)dst = p;
}

__device__ __forceinline__ void stage16(u16* dst, const float* src) {
    const f32x4* s = (const f32x4*)src;
    f32x4 v0 = s[0], v1 = s[1];
    cvt_store8(dst, v0, v1);
    f32x4 v2 = s[2], v3 = s[3];
    cvt_store8(dst + 8, v2, v3);
}

// ---------------- routing: build padded per-expert token lists ----------------
__global__ void route_kernel(const int* __restrict__ idx,
                             const float* __restrict__ w,
                             int* __restrict__ cnt, int* __restrict__ poff,
                             int* __restrict__ tok, float* __restrict__ wgt) {
    __shared__ int s_cnt[NEXP];
    __shared__ int s_off[NEXP + 1];
    __shared__ int s_cur[NEXP];
    int tid = threadIdx.x;
    if (tid < NEXP) { s_cnt[tid] = 0; s_cur[tid] = 0; }
    __syncthreads();
    for (int a = tid; a < NASSIGN; a += blockDim.x)
        atomicAdd(&s_cnt[idx[a]], 1);
    // init padded arrays: token 0 / weight 0 (padding rows become no-ops downstream)
    for (int i = tid; i < ROWCAP; i += blockDim.x) { tok[i] = 0; wgt[i] = 0.0f; }
    __syncthreads();
    if (tid == 0) {
        int o = 0;
        for (int e = 0; e < NEXP; ++e) { s_off[e] = o; o += (s_cnt[e] + 127) & ~127; }
        s_off[NEXP] = o;
    }
    __syncthreads();
    for (int a = tid; a < NASSIGN; a += blockDim.x) {
        int e = idx[a];
        int slot = atomicAdd(&s_cur[e], 1);
        int p = s_off[e] + slot;
        tok[p] = a >> 1;         // token id (a = t*TOPK + k)
        wgt[p] = w[a];
    }
    if (tid < NEXP) cnt[tid] = s_cnt[tid];
    if (tid <= NEXP) poff[tid] = s_off[tid];
}

// ---------------- phase A: h = silu(x@Wg^T) * (x@Wu^T), bf16 to ws ----------------
__global__ __launch_bounds__(256) void
moe_gateup_kernel(const float* __restrict__ x,
                  const float* __restrict__ gate,
                  const float* __restrict__ up,
                  const int* __restrict__ poff,
                  const int* __restrict__ tok,
                  u16* __restrict__ hbuf) {
    int e    = blockIdx.z;
    int base = poff[e];
    int pc   = poff[e + 1] - base;        // padded count, multiple of 128
    int m0   = blockIdx.y * 128;
    if (m0 >= pc) return;
    int n0 = blockIdx.x * 128;

    __shared__ __align__(16) u16 As[128][LDK];
    __shared__ __align__(16) u16 Bg[128][LDK];
    __shared__ __align__(16) u16 Bu[128][LDK];

    int tid  = threadIdx.x;
    int srow = tid >> 1;
    int scol = (tid & 1) * 16;

    int t = tok[base + m0 + srow];
    const float* pa = x    + (size_t)t * HDIM + scol;
    const float* pg = gate + ((size_t)e * IDIM + (n0 + srow)) * (size_t)HDIM + scol;
    const float* pu = up   + ((size_t)e * IDIM + (n0 + srow)) * (size_t)HDIM + scol;

    int lane = tid & 63;
    int wv   = tid >> 6;
    int wr   = (wv >> 1) * 64;
    int wc   = (wv & 1) * 64;
    int fr   = lane & 15;
    int fk   = (lane >> 4) * 8;

    f32x4 accg[4][4], accu[4][4];
#pragma unroll
    for (int i = 0; i < 4; ++i)
#pragma unroll
        for (int j = 0; j < 4; ++j) { accg[i][j] = (f32x4)0.0f; accu[i][j] = (f32x4)0.0f; }

    for (int k0 = 0; k0 < HDIM; k0 += BK) {
        __syncthreads();
        stage16(&As[srow][scol], pa + k0);
        stage16(&Bg[srow][scol], pg + k0);
        stage16(&Bu[srow][scol], pu + k0);
        __syncthreads();

        i32x4 af[4], bg[4], bu[4];
#pragma unroll
        for (int mf = 0; mf < 4; ++mf) af[mf] = *(const i32x4*)&As[wr + mf * 16 + fr][fk];
#pragma unroll
        for (int nf = 0; nf < 4; ++nf) {
            bg[nf] = *(const i32x4*)&Bg[wc + nf * 16 + fr][fk];
            bu[nf] = *(const i32x4*)&Bu[wc + nf * 16 + fr][fk];
        }
#pragma unroll
        for (int mf = 0; mf < 4; ++mf)
#pragma unroll
            for (int nf = 0; nf < 4; ++nf) {
                accg[mf][nf] = mfma16(af[mf], bg[nf], accg[mf][nf]);
                accu[mf][nf] = mfma16(af[mf], bu[nf], accu[mf][nf]);
            }
    }

    // epilogue: SiLU(g)*u -> bf16 h rows (C/D layout: col=lane&15, row=(lane>>4)*4+reg)
#pragma unroll
    for (int mf = 0; mf < 4; ++mf) {
#pragma unroll
        for (int j = 0; j < 4; ++j) {
            int row = wr + mf * 16 + (lane >> 4) * 4 + j;
            size_t hrow = (size_t)(base + m0 + row);
#pragma unroll
            for (int nf = 0; nf < 4; ++nf) {
                float g = accg[mf][nf][j];
                float u = accu[mf][nf][j];
                float sg = 1.0f / (1.0f + __expf(-g));
                float hv = g * sg * u;
                int col = n0 + wc + nf * 16 + fr;
                hbuf[hrow * IDIM + col] = f2bf(hv);
            }
        }
    }
}

// ---------------- phase B: out[t] += (h @ Wd^T) * w, atomic scatter ----------------
__global__ __launch_bounds__(256) void
moe_down_kernel(const u16* __restrict__ hbuf,
                const float* __restrict__ down,
                const int* __restrict__ poff,
                const int* __restrict__ tok,
                const float* __restrict__ wgt,
                float* __restrict__ out) {
    int e    = blockIdx.z;
    int base = poff[e];
    int pc   = poff[e + 1] - base;
    int m0   = blockIdx.y * 128;
    if (m0 >= pc) return;
    int n0 = blockIdx.x * 128;

    __shared__ __align__(16) u16 Ah[128][LDK];
    __shared__ __align__(16) u16 Bd[128][LDK];

    int tid  = threadIdx.x;
    int srow = tid >> 1;
    int scol = (tid & 1) * 16;

    const u16*   ph = hbuf + (size_t)(base + m0 + srow) * IDIM + scol;
    const float* pd = down + ((size_t)e * HDIM + (n0 + srow)) * (size_t)IDIM + scol;

    int lane = tid & 63;
    int wv   = tid >> 6;
    int wr   = (wv >> 1) * 64;
    int wc   = (wv & 1) * 64;
    int fr   = lane & 15;
    int fk   = (lane >> 4) * 8;

    f32x4 acc[4][4];
#pragma unroll
    for (int i = 0; i < 4; ++i)
#pragma unroll
        for (int j = 0; j < 4; ++j) acc[i][j] = (f32x4)0.0f;

    for (int k0 = 0; k0 < IDIM; k0 += BK) {
        __syncthreads();
        *(u16x8*)&Ah[srow][scol]     = *(const u16x8*)(ph + k0);
        *(u16x8*)&Ah[srow][scol + 8] = *(const u16x8*)(ph + k0 + 8);
        stage16(&Bd[srow][scol], pd + k0);
        __syncthreads();

        i32x4 af[4], bf[4];
#pragma unroll
        for (int mf = 0; mf < 4; ++mf) af[mf] = *(const i32x4*)&Ah[wr + mf * 16 + fr][fk];
#pragma unroll
        for (int nf = 0; nf < 4; ++nf) bf[nf] = *(const i32x4*)&Bd[wc + nf * 16 + fr][fk];
#pragma unroll
        for (int mf = 0; mf < 4; ++mf)
#pragma unroll
            for (int nf = 0; nf < 4; ++nf)
                acc[mf][nf] = mfma16(af[mf], bf[nf], acc[mf][nf]);
    }

#pragma unroll
    for (int mf = 0; mf < 4; ++mf) {
#pragma unroll
        for (int j = 0; j < 4; ++j) {
            int row = wr + mf * 16 + (lane >> 4) * 4 + j;
            int hr  = base + m0 + row;
            int t   = tok[hr];
            float w = wgt[hr];
            if (w != 0.0f) {
#pragma unroll
                for (int nf = 0; nf < 4; ++nf) {
                    int col = n0 + wc + nf * 16 + fr;
                    atomicAdd(&out[(size_t)t * HDIM + col], acc[mf][nf][j] * w);
                }
            }
        }
    }
}

extern "C" void kernel_launch(void* const* d_in, const int* in_sizes, int n_in,
                              void* d_out, int out_size, void* d_ws, size_t ws_size,
                              hipStream_t stream) {
    const float* x    = (const float*)d_in[0];
    const int*   eidx = (const int*)d_in[1];
    const float* ew   = (const float*)d_in[2];
    const float* gate = (const float*)d_in[3];
    const float* up   = (const float*)d_in[4];
    const float* down = (const float*)d_in[5];
    float* out = (float*)d_out;

    char* ws   = (char*)d_ws;
    int*  cnt  = (int*)ws;                       // 8 ints
    int*  poff = (int*)(ws + 64);                // 9 ints
    int*  tok  = (int*)(ws + 1024);              // ROWCAP ints
    float* wgt = (float*)(ws + 1024 + ROWCAP * 4);
    u16*  hbuf = (u16*)(ws + 65536);             // ROWCAP x IDIM bf16 (~73.4 MB)

    route_kernel<<<1, 256, 0, stream>>>(eidx, ew, cnt, poff, tok, wgt);
    hipMemsetAsync(d_out, 0, (size_t)TTOK * HDIM * sizeof(float), stream);

    dim3 gA(IDIM / 128, 32, NEXP);   // n-tiles x max-m-tiles x experts
    moe_gateup_kernel<<<gA, 256, 0, stream>>>(x, gate, up, poff, tok, hbuf);

    dim3 gB(HDIM / 128, 32, NEXP);
    moe_down_kernel<<<gB, 256, 0, stream>>>(hbuf, down, poff, tok, wgt, out);
}

// Round 2
// 1069.201 us; speedup vs baseline: 1.1811x; 1.1811x over previous
//
#include <hip/hip_runtime.h>
#include <hip/hip_bf16.h>
#include <math.h>

// Problem constants
#define HDIM 2048
#define IDIM 7168
#define NEXP 8
#define TTOK 2048
#define TOPK 2
#define NASSIGN (TTOK * TOPK)
#define ROWCAP 5120
#define BK 32
#define LDK 40   // fallback-path LDS padding

typedef float  f32x4 __attribute__((ext_vector_type(4)));
typedef int    i32x4 __attribute__((ext_vector_type(4)));
typedef unsigned short u16;
typedef u16    u16x8 __attribute__((ext_vector_type(8)));

__device__ __forceinline__ u16 f2bf(float f) {
    return __builtin_bit_cast(u16, (__bf16)f);
}

__device__ __forceinline__ f32x4 mfma16(i32x4 a, i32x4 b, f32x4 c) {
    asm("v_mfma_f32_16x16x32_bf16 %0, %1, %2, %0" : "+v"(c) : "v"(a), "v"(b));
    return c;
}

// async global->LDS, 16B per lane; LDS dest must be linear in lane order
#define GLD(gsrc, ldst) __builtin_amdgcn_global_load_lds( \
    (const __attribute__((address_space(1))) void*)(gsrc), \
    (__attribute__((address_space(3))) void*)(ldst), 16, 0, 0)

__device__ __forceinline__ void cvt_store8(u16* dst, f32x4 a, f32x4 b) {
    u16x8 p;
    p[0]=f2bf(a[0]); p[1]=f2bf(a[1]); p[2]=f2bf(a[2]); p[3]=f2bf(a[3]);
    p[4]=f2bf(b[0]); p[5]=f2bf(b[1]); p[6]=f2bf(b[2]); p[7]=f2bf(b[3]);
    *(u16x8*)dst = p;
}

__device__ __forceinline__ void stage16(u16* dst, const float* src) {
    const f32x4* s = (const f32x4*)src;
    f32x4 v0 = s[0], v1 = s[1];
    cvt_store8(dst, v0, v1);
    f32x4 v2 = s[2], v3 = s[3];
    cvt_store8(dst + 8, v2, v3);
}

// ---------------- routing ----------------
__global__ void route_kernel(const int* __restrict__ idx,
                             const float* __restrict__ w,
                             int* __restrict__ cnt, int* __restrict__ poff,
                             int* __restrict__ tok, float* __restrict__ wgt) {
    __shared__ int s_cnt[NEXP];
    __shared__ int s_off[NEXP + 1];
    __shared__ int s_cur[NEXP];
    int tid = threadIdx.x;
    if (tid < NEXP) { s_cnt[tid] = 0; s_cur[tid] = 0; }
    __syncthreads();
    for (int a = tid; a < NASSIGN; a += blockDim.x)
        atomicAdd(&s_cnt[idx[a]], 1);
    for (int i = tid; i < ROWCAP; i += blockDim.x) { tok[i] = 0; wgt[i] = 0.0f; }
    __syncthreads();
    if (tid == 0) {
        int o = 0;
        for (int e = 0; e < NEXP; ++e) { s_off[e] = o; o += (s_cnt[e] + 127) & ~127; }
        s_off[NEXP] = o;
    }
    __syncthreads();
    for (int a = tid; a < NASSIGN; a += blockDim.x) {
        int e = idx[a];
        int slot = atomicAdd(&s_cur[e], 1);
        int p = s_off[e] + slot;
        tok[p] = a >> 1;
        wgt[p] = w[a];
    }
    if (tid < NEXP) cnt[tid] = s_cnt[tid];
    if (tid <= NEXP) poff[tid] = s_off[tid];
}

// ---------------- fp32 -> bf16 streaming convert ----------------
__global__ __launch_bounds__(256) void cvt_bf16_kernel(const float* __restrict__ src,
                                                       u16* __restrict__ dst,
                                                       long long n8) {
    long long i = (long long)blockIdx.x * blockDim.x + threadIdx.x;
    long long stride = (long long)gridDim.x * blockDim.x;
    for (; i < n8; i += stride) {
        const f32x4* s = (const f32x4*)(src + i * 8);
        f32x4 a = s[0], b = s[1];
        u16x8 p;
        p[0]=f2bf(a[0]); p[1]=f2bf(a[1]); p[2]=f2bf(a[2]); p[3]=f2bf(a[3]);
        p[4]=f2bf(b[0]); p[5]=f2bf(b[1]); p[6]=f2bf(b[2]); p[7]=f2bf(b[3]);
        *(u16x8*)(dst + i * 8) = p;
    }
}

// ================= bf16 path (m97-style: global_load_lds + chunk-XOR swizzle) =================
// LDS tile: [128 rows][32 cols] bf16, rows of 4x16B chunks. Chunk at LDS slot s of
// row r holds GLOBAL chunk c = s ^ ((r>>1)&3)  (inverse-swizzled source, swizzled read).

__global__ __launch_bounds__(256) void
moe_gateup_bf16(const u16* __restrict__ xbf,
                const u16* __restrict__ gbf,
                const u16* __restrict__ ubf,
                const int* __restrict__ poff,
                const int* __restrict__ tok,
                u16* __restrict__ hbuf) {
    int e    = blockIdx.z;
    int base = poff[e];
    int pc   = poff[e + 1] - base;
    int m0   = blockIdx.y * 128;
    if (m0 >= pc) return;
    int n0 = blockIdx.x * 128;

    __shared__ __align__(16) u16 As[128 * 32];
    __shared__ __align__(16) u16 Bg[128 * 32];
    __shared__ __align__(16) u16 Bu[128 * 32];

    int tid = threadIdx.x;
    // two 16B chunks per thread per matrix: chunk ids q0=tid, q1=tid+256
    int r0 = tid >> 2, s0 = tid & 3;
    int r1 = r0 + 64;
    int c0 = s0 ^ ((r0 >> 1) & 3);
    int c1 = s0 ^ ((r1 >> 1) & 3);

    const u16* pa0 = xbf + (size_t)tok[base + m0 + r0] * HDIM + c0 * 8;
    const u16* pa1 = xbf + (size_t)tok[base + m0 + r1] * HDIM + c1 * 8;
    const u16* pg0 = gbf + ((size_t)e * IDIM + n0 + r0) * HDIM + c0 * 8;
    const u16* pg1 = gbf + ((size_t)e * IDIM + n0 + r1) * HDIM + c1 * 8;
    const u16* pu0 = ubf + ((size_t)e * IDIM + n0 + r0) * HDIM + c0 * 8;
    const u16* pu1 = ubf + ((size_t)e * IDIM + n0 + r1) * HDIM + c1 * 8;
    u16* lA0 = &As[tid * 8]; u16* lA1 = &As[(tid + 256) * 8];
    u16* lG0 = &Bg[tid * 8]; u16* lG1 = &Bg[(tid + 256) * 8];
    u16* lU0 = &Bu[tid * 8]; u16* lU1 = &Bu[(tid + 256) * 8];

    int lane = tid & 63;
    int wv   = tid >> 6;
    int wr   = (wv >> 1) * 64;
    int wc   = (wv & 1) * 64;
    int fr   = lane & 15;
    int cc   = lane >> 4;         // wanted global chunk (fk = cc*8)

    int offA[4], offB[4];
#pragma unroll
    for (int mf = 0; mf < 4; ++mf) {
        int R = wr + mf * 16 + fr;
        offA[mf] = R * 32 + (cc ^ ((R >> 1) & 3)) * 8;
    }
#pragma unroll
    for (int nf = 0; nf < 4; ++nf) {
        int R = wc + nf * 16 + fr;
        offB[nf] = R * 32 + (cc ^ ((R >> 1) & 3)) * 8;
    }

    f32x4 accg[4][4], accu[4][4];
#pragma unroll
    for (int i = 0; i < 4; ++i)
#pragma unroll
        for (int j = 0; j < 4; ++j) { accg[i][j] = (f32x4)0.0f; accu[i][j] = (f32x4)0.0f; }

    for (int k0 = 0; k0 < HDIM; k0 += BK) {
        __syncthreads();
        GLD(pa0, lA0); GLD(pa1, lA1);
        GLD(pg0, lG0); GLD(pg1, lG1);
        GLD(pu0, lU0); GLD(pu1, lU1);
        pa0 += BK; pa1 += BK; pg0 += BK; pg1 += BK; pu0 += BK; pu1 += BK;
        __syncthreads();

        i32x4 af[4], bg[4], bu[4];
#pragma unroll
        for (int mf = 0; mf < 4; ++mf) af[mf] = *(const i32x4*)&As[offA[mf]];
#pragma unroll
        for (int nf = 0; nf < 4; ++nf) {
            bg[nf] = *(const i32x4*)&Bg[offB[nf]];
            bu[nf] = *(const i32x4*)&Bu[offB[nf]];
        }
#pragma unroll
        for (int mf = 0; mf < 4; ++mf)
#pragma unroll
            for (int nf = 0; nf < 4; ++nf) {
                accg[mf][nf] = mfma16(af[mf], bg[nf], accg[mf][nf]);
                accu[mf][nf] = mfma16(af[mf], bu[nf], accu[mf][nf]);
            }
    }

#pragma unroll
    for (int mf = 0; mf < 4; ++mf) {
#pragma unroll
        for (int j = 0; j < 4; ++j) {
            int row = wr + mf * 16 + (lane >> 4) * 4 + j;
            size_t hrow = (size_t)(base + m0 + row);
#pragma unroll
            for (int nf = 0; nf < 4; ++nf) {
                float g = accg[mf][nf][j];
                float u = accu[mf][nf][j];
                float sg = 1.0f / (1.0f + __expf(-g));
                hbuf[hrow * IDIM + n0 + wc + nf * 16 + fr] = f2bf(g * sg * u);
            }
        }
    }
}

__global__ __launch_bounds__(256) void
moe_down_bf16(const u16* __restrict__ hbuf,
              const u16* __restrict__ dbf,
              const int* __restrict__ poff,
              const int* __restrict__ tok,
              const float* __restrict__ wgt,
              float* __restrict__ out) {
    int e    = blockIdx.z;
    int base = poff[e];
    int pc   = poff[e + 1] - base;
    int m0   = blockIdx.y * 128;
    if (m0 >= pc) return;
    int n0 = blockIdx.x * 128;

    __shared__ __align__(16) u16 Ah[128 * 32];
    __shared__ __align__(16) u16 Bd[128 * 32];

    int tid = threadIdx.x;
    int r0 = tid >> 2, s0 = tid & 3;
    int r1 = r0 + 64;
    int c0 = s0 ^ ((r0 >> 1) & 3);
    int c1 = s0 ^ ((r1 >> 1) & 3);

    const u16* ph0 = hbuf + (size_t)(base + m0 + r0) * IDIM + c0 * 8;
    const u16* ph1 = hbuf + (size_t)(base + m0 + r1) * IDIM + c1 * 8;
    const u16* pd0 = dbf + ((size_t)e * HDIM + n0 + r0) * IDIM + c0 * 8;
    const u16* pd1 = dbf + ((size_t)e * HDIM + n0 + r1) * IDIM + c1 * 8;
    u16* lA0 = &Ah[tid * 8]; u16* lA1 = &Ah[(tid + 256) * 8];
    u16* lB0 = &Bd[tid * 8]; u16* lB1 = &Bd[(tid + 256) * 8];

    int lane = tid & 63;
    int wv   = tid >> 6;
    int wr   = (wv >> 1) * 64;
    int wc   = (wv & 1) * 64;
    int fr   = lane & 15;
    int cc   = lane >> 4;

    int offA[4], offB[4];
#pragma unroll
    for (int mf = 0; mf < 4; ++mf) {
        int R = wr + mf * 16 + fr;
        offA[mf] = R * 32 + (cc ^ ((R >> 1) & 3)) * 8;
    }
#pragma unroll
    for (int nf = 0; nf < 4; ++nf) {
        int R = wc + nf * 16 + fr;
        offB[nf] = R * 32 + (cc ^ ((R >> 1) & 3)) * 8;
    }

    f32x4 acc[4][4];
#pragma unroll
    for (int i = 0; i < 4; ++i)
#pragma unroll
        for (int j = 0; j < 4; ++j) acc[i][j] = (f32x4)0.0f;

    for (int k0 = 0; k0 < IDIM; k0 += BK) {
        __syncthreads();
        GLD(ph0, lA0); GLD(ph1, lA1);
        GLD(pd0, lB0); GLD(pd1, lB1);
        ph0 += BK; ph1 += BK; pd0 += BK; pd1 += BK;
        __syncthreads();

        i32x4 af[4], bf_[4];
#pragma unroll
        for (int mf = 0; mf < 4; ++mf) af[mf] = *(const i32x4*)&Ah[offA[mf]];
#pragma unroll
        for (int nf = 0; nf < 4; ++nf) bf_[nf] = *(const i32x4*)&Bd[offB[nf]];
#pragma unroll
        for (int mf = 0; mf < 4; ++mf)
#pragma unroll
            for (int nf = 0; nf < 4; ++nf)
                acc[mf][nf] = mfma16(af[mf], bf_[nf], acc[mf][nf]);
    }

#pragma unroll
    for (int mf = 0; mf < 4; ++mf) {
#pragma unroll
        for (int j = 0; j < 4; ++j) {
            int row = wr + mf * 16 + (lane >> 4) * 4 + j;
            int hr  = base + m0 + row;
            int t   = tok[hr];
            float w = wgt[hr];
            if (w != 0.0f) {
#pragma unroll
                for (int nf = 0; nf < 4; ++nf) {
                    int col = n0 + wc + nf * 16 + fr;
                    atomicAdd(&out[(size_t)t * HDIM + col], acc[mf][nf][j] * w);
                }
            }
        }
    }
}

// ================= fp32 fallback (round-0, known-good) =================
__global__ __launch_bounds__(256) void
moe_gateup_f32(const float* __restrict__ x, const float* __restrict__ gate,
               const float* __restrict__ up, const int* __restrict__ poff,
               const int* __restrict__ tok, u16* __restrict__ hbuf) {
    int e = blockIdx.z;
    int base = poff[e];
    int pc = poff[e + 1] - base;
    int m0 = blockIdx.y * 128;
    if (m0 >= pc) return;
    int n0 = blockIdx.x * 128;
    __shared__ __align__(16) u16 As[128][LDK];
    __shared__ __align__(16) u16 Bg[128][LDK];
    __shared__ __align__(16) u16 Bu[128][LDK];
    int tid = threadIdx.x;
    int srow = tid >> 1;
    int scol = (tid & 1) * 16;
    int t = tok[base + m0 + srow];
    const float* pa = x + (size_t)t * HDIM + scol;
    const float* pg = gate + ((size_t)e * IDIM + (n0 + srow)) * (size_t)HDIM + scol;
    const float* pu = up + ((size_t)e * IDIM + (n0 + srow)) * (size_t)HDIM + scol;
    int lane = tid & 63;
    int wv = tid >> 6;
    int wr = (wv >> 1) * 64;
    int wc = (wv & 1) * 64;
    int fr = lane & 15;
    int fk = (lane >> 4) * 8;
    f32x4 accg[4][4], accu[4][4];
#pragma unroll
    for (int i = 0; i < 4; ++i)
#pragma unroll
        for (int j = 0; j < 4; ++j) { accg[i][j] = (f32x4)0.0f; accu[i][j] = (f32x4)0.0f; }
    for (int k0 = 0; k0 < HDIM; k0 += BK) {
        __syncthreads();
        stage16(&As[srow][scol], pa + k0);
        stage16(&Bg[srow][scol], pg + k0);
        stage16(&Bu[srow][scol], pu + k0);
        __syncthreads();
        i32x4 af[4], bg[4], bu[4];
#pragma unroll
        for (int mf = 0; mf < 4; ++mf) af[mf] = *(const i32x4*)&As[wr + mf * 16 + fr][fk];
#pragma unroll
        for (int nf = 0; nf < 4; ++nf) {
            bg[nf] = *(const i32x4*)&Bg[wc + nf * 16 + fr][fk];
            bu[nf] = *(const i32x4*)&Bu[wc + nf * 16 + fr][fk];
        }
#pragma unroll
        for (int mf = 0; mf < 4; ++mf)
#pragma unroll
            for (int nf = 0; nf < 4; ++nf) {
                accg[mf][nf] = mfma16(af[mf], bg[nf], accg[mf][nf]);
                accu[mf][nf] = mfma16(af[mf], bu[nf], accu[mf][nf]);
            }
    }
#pragma unroll
    for (int mf = 0; mf < 4; ++mf) {
#pragma unroll
        for (int j = 0; j < 4; ++j) {
            int row = wr + mf * 16 + (lane >> 4) * 4 + j;
            size_t hrow = (size_t)(base + m0 + row);
#pragma unroll
            for (int nf = 0; nf < 4; ++nf) {
                float g = accg[mf][nf][j];
                float u = accu[mf][nf][j];
                float sg = 1.0f / (1.0f + __expf(-g));
                hbuf[hrow * IDIM + n0 + wc + nf * 16 + fr] = f2bf(g * sg * u);
            }
        }
    }
}

__global__ __launch_bounds__(256) void
moe_down_f32(const u16* __restrict__ hbuf, const float* __restrict__ down,
             const int* __restrict__ poff, const int* __restrict__ tok,
             const float* __restrict__ wgt, float* __restrict__ out) {
    int e = blockIdx.z;
    int base = poff[e];
    int pc = poff[e + 1] - base;
    int m0 = blockIdx.y * 128;
    if (m0 >= pc) return;
    int n0 = blockIdx.x * 128;
    __shared__ __align__(16) u16 Ah[128][LDK];
    __shared__ __align__(16) u16 Bd[128][LDK];
    int tid = threadIdx.x;
    int srow = tid >> 1;
    int scol = (tid & 1) * 16;
    const u16* ph = hbuf + (size_t)(base + m0 + srow) * IDIM + scol;
    const float* pd = down + ((size_t)e * HDIM + (n0 + srow)) * (size_t)IDIM + scol;
    int lane = tid & 63;
    int wv = tid >> 6;
    int wr = (wv >> 1) * 64;
    int wc = (wv & 1) * 64;
    int fr = lane & 15;
    int fk = (lane >> 4) * 8;
    f32x4 acc[4][4];
#pragma unroll
    for (int i = 0; i < 4; ++i)
#pragma unroll
        for (int j = 0; j < 4; ++j) acc[i][j] = (f32x4)0.0f;
    for (int k0 = 0; k0 < IDIM; k0 += BK) {
        __syncthreads();
        *(u16x8*)&Ah[srow][scol] = *(const u16x8*)(ph + k0);
        *(u16x8*)&Ah[srow][scol + 8] = *(const u16x8*)(ph + k0 + 8);
        stage16(&Bd[srow][scol], pd + k0);
        __syncthreads();
        i32x4 af[4], bf_[4];
#pragma unroll
        for (int mf = 0; mf < 4; ++mf) af[mf] = *(const i32x4*)&Ah[wr + mf * 16 + fr][fk];
#pragma unroll
        for (int nf = 0; nf < 4; ++nf) bf_[nf] = *(const i32x4*)&Bd[wc + nf * 16 + fr][fk];
#pragma unroll
        for (int mf = 0; mf < 4; ++mf)
#pragma unroll
            for (int nf = 0; nf < 4; ++nf)
                acc[mf][nf] = mfma16(af[mf], bf_[nf], acc[mf][nf]);
    }
#pragma unroll
    for (int mf = 0; mf < 4; ++mf) {
#pragma unroll
        for (int j = 0; j < 4; ++j) {
            int row = wr + mf * 16 + (lane >> 4) * 4 + j;
            int hr = base + m0 + row;
            int t = tok[hr];
            float w = wgt[hr];
            if (w != 0.0f) {
#pragma unroll
                for (int nf = 0; nf < 4; ++nf) {
                    int col = n0 + wc + nf * 16 + fr;
                    atomicAdd(&out[(size_t)t * HDIM + col], acc[mf][nf][j] * w);
                }
            }
        }
    }
}

extern "C" void kernel_launch(void* const* d_in, const int* in_sizes, int n_in,
                              void* d_out, int out_size, void* d_ws, size_t ws_size,
                              hipStream_t stream) {
    const float* x    = (const float*)d_in[0];
    const int*   eidx = (const int*)d_in[1];
    const float* ew   = (const float*)d_in[2];
    const float* gate = (const float*)d_in[3];
    const float* up   = (const float*)d_in[4];
    const float* down = (const float*)d_in[5];
    float* out = (float*)d_out;

    char* ws   = (char*)d_ws;
    int*  cnt  = (int*)ws;
    int*  poff = (int*)(ws + 64);
    int*  tok  = (int*)(ws + 1024);
    float* wgt = (float*)(ws + 1024 + ROWCAP * 4);

    const size_t xbf_sz = (size_t)TTOK * HDIM * 2;                 // 8 MB
    const size_t w_sz   = (size_t)NEXP * IDIM * HDIM * 2;          // ~235 MB
    const size_t h_sz   = (size_t)ROWCAP * IDIM * 2;               // ~73 MB
    const size_t xbf_off = 65536;
    const size_t g_off   = xbf_off + xbf_sz;
    const size_t u_off   = g_off + w_sz;
    const size_t h_off   = u_off + w_sz;
    const size_t need    = h_off + h_sz;

    route_kernel<<<1, 256, 0, stream>>>(eidx, ew, cnt, poff, tok, wgt);
    hipMemsetAsync(d_out, 0, (size_t)TTOK * HDIM * sizeof(float), stream);

    if (ws_size >= need) {
        u16* xbf = (u16*)(ws + xbf_off);
        u16* gbf = (u16*)(ws + g_off);
        u16* ubf = (u16*)(ws + u_off);
        u16* hb  = (u16*)(ws + h_off);
        u16* dbf = gbf;  // alias: down conversion runs after gateup completes

        long long nw8 = (long long)NEXP * IDIM * HDIM / 8;
        cvt_bf16_kernel<<<1024, 256, 0, stream>>>(x, xbf, (long long)TTOK * HDIM / 8);
        cvt_bf16_kernel<<<2048, 256, 0, stream>>>(gate, gbf, nw8);
        cvt_bf16_kernel<<<2048, 256, 0, stream>>>(up, ubf, nw8);

        dim3 gA(IDIM / 128, 32, NEXP);
        moe_gateup_bf16<<<gA, 256, 0, stream>>>(xbf, gbf, ubf, poff, tok, hb);

        cvt_bf16_kernel<<<2048, 256, 0, stream>>>(down, dbf, nw8);

        dim3 gB(HDIM / 128, 32, NEXP);
        moe_down_bf16<<<gB, 256, 0, stream>>>(hb, dbf, poff, tok, wgt, out);
    } else {
        u16* hb = (u16*)(ws + 65536);
        dim3 gA(IDIM / 128, 32, NEXP);
        moe_gateup_f32<<<gA, 256, 0, stream>>>(x, gate, up, poff, tok, hb);
        dim3 gB(HDIM / 128, 32, NEXP);
        moe_down_f32<<<gB, 256, 0, stream>>>(hb, down, poff, tok, wgt, out);
    }
}